// Round 1
// baseline (1715.816 us; speedup 1.0000x reference)
//
#include <hip/hip_runtime.h>
#include <hip/hip_bf16.h>
#include <stdint.h>

typedef __attribute__((ext_vector_type(8))) __bf16 bf16x8;
typedef __attribute__((ext_vector_type(4))) float  floatx4;
typedef __attribute__((ext_vector_type(4))) unsigned int uintx4;

#define T_STEPS 256
#define BATCH   128
#define HID     512
// Sentinel: memset byte 0x7F -> bf16 0x7F7F = 3.39e38. h = (1-z)*n + z*h_prev
// with n = tanh(..) is strictly inside (-1,1) (bf16 rounding can reach +-1.0),
// so no legitimate stored word can equal 0x7F7F7F7F.
#define SENTW 0x7F7F7F7Fu

__device__ __forceinline__ float sigmoidf_(float x) { return 1.f / (1.f + __expf(-x)); }
__device__ __forceinline__ float tanhf_(float y) {
  float e = __expf(-2.f * fabsf(y));
  return copysignf((1.f - e) / (1.f + e), y);
}

__device__ __forceinline__ bool okw_(uintx4 w) {
  return (w[0] != SENTW) & (w[1] != SENTW) & (w[2] != SENTW) & (w[3] != SENTW);
}

// Self-validating fragment load: 16 chunks x 16B per lane, polled until no
// chunk contains the sentinel. sc0 sc1 bypasses L1+L2 so stores that landed
// at the memory-side coherence point (L3) are visible regardless of XCD.
// Each 4B word is written exactly once by its producer (dword stores are
// single-copy atomic), so "word != sentinel" == "word is final".
// Retries reload only pending chunks; per-lane pend mask, exec-masked.
__device__ __forceinline__ void sentload16_(const __bf16* base, uintx4* hw) {
  unsigned pend = 0xFFFFu;
  while (pend) {
    #pragma unroll
    for (int kt = 0; kt < 16; ++kt)
      if (pend & (1u << kt)) {
        const void* p = (const void*)(base + kt * 32);
        asm volatile("global_load_dwordx4 %0, %1, off sc0 sc1"
                     : "=v"(hw[kt]) : "v"(p));
      }
    asm volatile("s_waitcnt vmcnt(0)" ::: "memory");
    __builtin_amdgcn_sched_barrier(0);   // rule #18: keep checks below the wait
    unsigned np = 0;
    #pragma unroll
    for (int kt = 0; kt < 16; ++kt)
      if (pend & (1u << kt)) {
        if (!okw_(hw[kt])) np |= (1u << kt);
      }
    pend = np;
    if (pend == 0xFFFFu) __builtin_amdgcn_s_sleep(4);  // nothing landed yet
    else if (pend)       __builtin_amdgcn_s_sleep(1);  // arriving now
  }
}

// Fused 2-layer persistent GRU scan, software-pipelined across layers.
// Grid = 256 blocks: [layer(2)][bg(2)][g(64)].
//   layer L, bg, g: owns hidden cols [8g,8g+8) for batch rows [64bg,64bg+64).
// h exchange (NEW this round): sentinel-dataflow, no flags/acks/barriers.
//   Slabs pre-memset to 0x7F. Producer: packed 4B relaxed AGENT stores only
//   (no vmcnt drain, no __syncthreads, no flag). Consumer: sc0-sc1 polled
//   b128 loads that self-validate against the sentinel (sentload16_).
//   Per-step chain = one-way store flight + poll detect (physical minimum).
//   Waves are fully independent (wave w only exchanges with wave w of the
//   64-block sub-ring); dataflow is acyclic (layer0 ring -> layer1) so no
//   deadlock; polls are s_sleep paced.
// Layer-0 phaseX reads x directly as fp32 [b][t][256] (cvt folded in), done
// right after the epilogue stores so the store flight hides under it.
__global__ __launch_bounds__(256) void gru_fused(
    const float* __restrict__ x,                              // [128][256][256] fp32
    const float* __restrict__ Wih0, const float* __restrict__ Whh0,
    const float* __restrict__ bih0, const float* __restrict__ bhh0,
    const float* __restrict__ Wih1, const float* __restrict__ Whh1,
    const float* __restrict__ bih1, const float* __restrict__ bhh1,
    __bf16* __restrict__ h0base,                              // [256][128][512]
    __bf16* __restrict__ h1base)                              // [256][128][512]
{
  const int tid   = threadIdx.x;
  const int layer = blockIdx.x >> 7;
  const int bg    = (blockIdx.x >> 6) & 1;
  const int g     = blockIdx.x & 63;
  const int w = tid >> 6, l = tid & 63, c = l & 15, q = l >> 4;
  const int Kin = layer ? HID : 256;
  const int KTx = Kin >> 5;            // 8 or 16
  const int KT  = KTx + 16;
  const int rowbase = bg * 64 + w * 16;
  const int jj  = g * 8 + c;

  const float* Wih = layer ? Wih1 : Wih0;
  const float* Whh = layer ? Whh1 : Whh0;
  const float* bih = layer ? bih1 : bih0;
  const float* bhh = layer ? bhh1 : bhh0;
  __bf16* hbase = layer ? h1base : h0base;

  __shared__ __bf16 ldsW[2 * 32 * 64 * 8];   // 64 KiB max (KT<=32)

  // ---- stage W slice (fp32 -> bf16) into frag-order LDS
  // tile0 cols: [r0..7 | z0..7], tile1 cols: [n0..7 | zeros]
  for (int cid = tid; cid < 2 * KT * 64; cid += 256) {
    int nt = cid / (KT * 64);
    int r1 = cid - nt * (KT * 64);
    int kt = r1 >> 6;
    int ll = r1 & 63;
    int cc = ll & 15, qq = ll >> 4;
    int k  = kt * 32 + qq * 8;
    int grow;
    if (nt == 0) grow = (cc < 8) ? (g * 8 + cc) : (512 + g * 8 + (cc - 8));
    else         grow = (cc < 8) ? (1024 + g * 8 + cc) : -1;
    bf16x8 v;
    if (grow >= 0) {
      const float* src = (k < Kin) ? (Wih + (size_t)grow * Kin + k)
                                   : (Whh + (size_t)grow * HID + (k - Kin));
      #pragma unroll
      for (int j = 0; j < 8; ++j) v[j] = (__bf16)src[j];
    } else {
      #pragma unroll
      for (int j = 0; j < 8; ++j) v[j] = (__bf16)0.f;
    }
    *(bf16x8*)&ldsW[((size_t)(nt * KT + kt) * 64 + ll) * 8] = v;
  }
  __syncthreads();   // only barrier in the kernel; LDS is read-only afterwards

  // ---- hoist the h-part W fragments
  bf16x8 WH[16][2];
  #pragma unroll
  for (int kt = 0; kt < 16; ++kt) {
    WH[kt][0] = *(const bf16x8*)&ldsW[((size_t)(0 * KT + KTx + kt) * 64 + l) * 8];
    WH[kt][1] = *(const bf16x8*)&ldsW[((size_t)(1 * KT + KTx + kt) * 64 + l) * 8];
  }

  // ---- per-lane biases
  float bias0, bias_nx, bias_nh;
  if (c < 8) {
    bias0   = bih[jj] + bhh[jj];
    bias_nx = bih[1024 + jj];
    bias_nh = bhh[1024 + jj];
  } else {
    int j2 = g * 8 + (c - 8);
    bias0   = bih[512 + j2] + bhh[512 + j2];
    bias_nx = 0.f; bias_nh = 0.f;
  }

  floatx4 accA[2], accB[2];
  const floatx4 zero4 = {0.f, 0.f, 0.f, 0.f};
  float hprev[4] = {0.f, 0.f, 0.f, 0.f};

  auto hslab = [&](int t) -> __bf16* {
    return hbase + (size_t)t * (BATCH * HID);
  };

  auto phaseX = [&](int t) {
    accA[0] = zero4; accA[1] = zero4;
    if (layer == 0) {
      const float* xp = x + ((size_t)(rowbase + c) * T_STEPS + t) * 256 + q * 8;
      for (int kt = 0; kt < 8; ++kt) {
        bf16x8 b0 = *(const bf16x8*)&ldsW[((size_t)(0 * KT + kt) * 64 + l) * 8];
        bf16x8 b1 = *(const bf16x8*)&ldsW[((size_t)(1 * KT + kt) * 64 + l) * 8];
        floatx4 u = *(const floatx4*)(xp + kt * 32);
        floatx4 v = *(const floatx4*)(xp + kt * 32 + 4);
        bf16x8 a;
        a[0] = (__bf16)u[0]; a[1] = (__bf16)u[1]; a[2] = (__bf16)u[2]; a[3] = (__bf16)u[3];
        a[4] = (__bf16)v[0]; a[5] = (__bf16)v[1]; a[6] = (__bf16)v[2]; a[7] = (__bf16)v[3];
        accA[0] = __builtin_amdgcn_mfma_f32_16x16x32_bf16(a, b0, accA[0], 0, 0, 0);
        accA[1] = __builtin_amdgcn_mfma_f32_16x16x32_bf16(a, b1, accA[1], 0, 0, 0);
      }
    } else {
      // x = h0 slab t: gated purely by dataflow (sentinel poll)
      const __bf16* xp = h0base + (size_t)t * (BATCH * HID)
                       + (size_t)(rowbase + c) * HID + q * 8;
      uintx4 aw[16];
      sentload16_(xp, aw);
      #pragma unroll
      for (int kt = 0; kt < 16; ++kt) {
        bf16x8 b0 = *(const bf16x8*)&ldsW[((size_t)(0 * KT + kt) * 64 + l) * 8];
        bf16x8 b1 = *(const bf16x8*)&ldsW[((size_t)(1 * KT + kt) * 64 + l) * 8];
        bf16x8 a  = __builtin_bit_cast(bf16x8, aw[kt]);
        accA[0] = __builtin_amdgcn_mfma_f32_16x16x32_bf16(a, b0, accA[0], 0, 0, 0);
        accA[1] = __builtin_amdgcn_mfma_f32_16x16x32_bf16(a, b1, accA[1], 0, 0, 0);
      }
    }
  };

  // ---- prologue (layer 1's phaseX(0) self-gates on h0 slab 0 via sentinel)
  phaseX(0);

  for (int t = 0; t < T_STEPS; ++t) {
    // ---- phase H: accB = h_{t-1} @ Whh_slice^T (sentinel-polled loads)
    accB[0] = zero4; accB[1] = zero4;
    if (t > 0) {
      const __bf16* hA = hslab(t - 1) + (size_t)(rowbase + c) * HID + q * 8;
      uintx4 hw[16];
      sentload16_(hA, hw);
      #pragma unroll
      for (int kt = 0; kt < 16; ++kt) {
        bf16x8 hf = __builtin_bit_cast(bf16x8, hw[kt]);
        accB[0] = __builtin_amdgcn_mfma_f32_16x16x32_bf16(hf, WH[kt][0], accB[0], 0, 0, 0);
        accB[1] = __builtin_amdgcn_mfma_f32_16x16x32_bf16(hf, WH[kt][1], accB[1], 0, 0, 0);
      }
    }

    // ---- epilogue: gates + h update; packed-pair agent stores, fire-and-forget
    __bf16* hs = hslab(t);
    #pragma unroll
    for (int rg = 0; rg < 4; ++rg) {
      float pre0 = accA[0][rg] + accB[0][rg] + bias0;
      float zs = __shfl(pre0, (l & 48) | ((c + 8) & 15), 64);
      float r  = sigmoidf_(pre0);
      float z  = sigmoidf_(zs);
      float nn = tanhf_(accA[1][rg] + bias_nx + r * (accB[1][rg] + bias_nh));
      float hnew = (1.f - z) * nn + z * hprev[rg];
      hprev[rg] = hnew;
      unsigned short us = __builtin_bit_cast(unsigned short, (__bf16)hnew);
      int po = __shfl_xor((int)us, 1, 64);
      if (c < 8 && (c & 1) == 0) {
        uint32_t v = (uint32_t)us | ((uint32_t)po << 16);
        int row = rowbase + q * 4 + rg;
        __hip_atomic_store((uint32_t*)(hs + (size_t)row * HID + jj), v,
                           __ATOMIC_RELAXED, __HIP_MEMORY_SCOPE_AGENT);
      }
    }
    // no vmcnt drain, no barrier, no flag: stores fly while phaseX computes;
    // consumers self-validate against the sentinel.

    if (t + 1 < T_STEPS) phaseX(t + 1);
  }
}

// yhat[b][o] = h1_last[b][:] . Wout[o][:] + bout[o]
__global__ __launch_bounds__(64) void outproj(const __bf16* __restrict__ h1,
                                              const float* __restrict__ Wout,
                                              const float* __restrict__ bout,
                                              float* __restrict__ out) {
  int b = blockIdx.x, o = threadIdx.x;
  const __bf16* hr = h1 + (size_t)b * HID;
  const float*  wr = Wout + (size_t)o * HID;
  float acc = bout[o];
  for (int k = 0; k < HID; k += 8) {
    bf16x8 h8 = *(const bf16x8*)(hr + k);
    #pragma unroll
    for (int j = 0; j < 8; ++j) acc += (float)h8[j] * wr[k + j];
  }
  out[b * 64 + o] = acc;
}

extern "C" void kernel_launch(void* const* d_in, const int* in_sizes, int n_in,
                              void* d_out, int out_size, void* d_ws, size_t ws_size,
                              hipStream_t stream) {
  const float* x    = (const float*)d_in[0];
  const float* Wih0 = (const float*)d_in[1];
  const float* Whh0 = (const float*)d_in[2];
  const float* bih0 = (const float*)d_in[3];
  const float* bhh0 = (const float*)d_in[4];
  const float* Wih1 = (const float*)d_in[5];
  const float* Whh1 = (const float*)d_in[6];
  const float* bih1 = (const float*)d_in[7];
  const float* bhh1 = (const float*)d_in[8];
  const float* Wout = (const float*)d_in[9];
  const float* bout = (const float*)d_in[10];

  char* ws = (char*)d_ws;
  // ws layout (bytes):
  //   [0, 32 MiB)        h0seq: 256 slabs x 128 KB ([t][b][512] bf16)
  //   [32 MiB, 64 MiB)   h1seq: 256 slabs x 128 KB
  __bf16* h0 = (__bf16*)(ws);
  __bf16* h1 = (__bf16*)(ws + (32u << 20));

  // sentinel-fill both h sequences (ws is poisoned before every launch);
  // 0x7F byte pattern -> bf16 0x7F7F, unreachable by any GRU hidden state
  (void)hipMemsetAsync(ws, 0x7F, (64u << 20), stream);

  // fused 2-layer pipelined scan: blocks [0,128) = layer 0, [128,256) = layer 1
  gru_fused<<<256, 256, 0, stream>>>(x,
                                     Wih0, Whh0, bih0, bhh0,
                                     Wih1, Whh1, bih1, bhh1,
                                     h0, h1);

  // final h1 = slab 255
  outproj<<<128, 64, 0, stream>>>(h1 + (size_t)255 * BATCH * HID,
                                  Wout, bout, (float*)d_out);
}